// Round 2
// baseline (2783.381 us; speedup 1.0000x reference)
//
#include <hip/hip_runtime.h>

// BinaryTTN on MI355X — round 2.
// Round-1 crash attributed to d_ws overflow (used 402 MB blind). Now: batch-chunked
// L0..L4 (8 chunks of 256) with per-chunk ping-pong buffers, L4 writes full-batch
// layout, L5..L11 full batch. Total ws = 67.1 MB.
// Layout for intermediates: act[site][n][16] (64B per (site,n) -> float4-coalesced).

#define NB 2048     // batch
#define CHUNK 256   // batch chunk for wide layers

typedef float f4 __attribute__((ext_vector_type(4)));

// ---------------- Layer 0: in_dim=2, pairs along H of the 64x64 grid ----------------
// x layout: (n, c=2, 64, 64). out: site = x0*64 + y (grid 32x64), layout [site][CHUNK][16]
__global__ __launch_bounds__(256) void ttn_l0(
    const float* __restrict__ x, float* __restrict__ out,
    const float* __restrict__ w0, int n0)
{
  const int x0   = blockIdx.x;          // 0..31
  const int y    = threadIdx.x & 63;    // 0..63 (coalesced dim)
  const int nsub = threadIdx.x >> 6;    // 0..3
  const int nloc = blockIdx.y * 4 + nsub;   // 0..CHUNK-1
  const int n    = n0 + nloc;

  const float* xb = x + (long)n * 8192 + (2 * x0) * 64 + y;
  const float l0 = xb[0];
  const float l1 = xb[4096];
  const float r0 = xb[64];
  const float r1 = xb[4096 + 64];
  const float p00 = l0 * r0, p01 = l0 * r1, p10 = l1 * r0, p11 = l1 * r1;

  const float* wp = w0 + (long)(x0 * 64 + y) * 64;  // (b,i,j) = b*4 + i*2 + j
  float acc[16];
#pragma unroll
  for (int b = 0; b < 16; ++b) {
    acc[b] = wp[b * 4 + 0] * p00 + wp[b * 4 + 1] * p01 +
             wp[b * 4 + 2] * p10 + wp[b * 4 + 3] * p11;
  }

  float* op = out + ((long)(x0 * 64 + y) * CHUNK + nloc) * 16;
#pragma unroll
  for (int c = 0; c < 4; ++c) {
    f4 v = {acc[4 * c + 0], acc[4 * c + 1], acc[4 * c + 2], acc[4 * c + 3]};
    *reinterpret_cast<f4*>(op + 4 * c) = v;
  }
}

// ---------------- Generic layer: in_dim=16, bond=16 ----------------
// in layout [site][nbIn][16]; out layout [site][nbOut][16] at n-offset nOff.
// W layout (h, w, 16, 16, 16), site-uniform per block -> scalar loads expected.
__global__ __launch_bounds__(256) void ttn_layer(
    const float* __restrict__ in, float* __restrict__ out,
    const float* __restrict__ w, int outW, int prevW, int pairW,
    int nbIn, int nbOut, int nOff)
{
  const int site = blockIdx.x;
  const int xs = site / outW;
  const int ys = site - xs * outW;
  int ls, rs;
  if (pairW) { ls = xs * prevW + 2 * ys; rs = ls + 1; }
  else       { ls = 2 * xs * prevW + ys; rs = ls + prevW; }

  const int nloc = blockIdx.y * 256 + threadIdx.x;

  const float* lp = in + ((long)ls * nbIn + nloc) * 16;
  const float* rp = in + ((long)rs * nbIn + nloc) * 16;
  float l[16], r[16];
#pragma unroll
  for (int c = 0; c < 4; ++c) {
    f4 lv = *reinterpret_cast<const f4*>(lp + 4 * c);
    f4 rv = *reinterpret_cast<const f4*>(rp + 4 * c);
    l[4 * c + 0] = lv.x; l[4 * c + 1] = lv.y; l[4 * c + 2] = lv.z; l[4 * c + 3] = lv.w;
    r[4 * c + 0] = rv.x; r[4 * c + 1] = rv.y; r[4 * c + 2] = rv.z; r[4 * c + 3] = rv.w;
  }

  const float* __restrict__ W = w + (long)site * 4096;  // (b,i,j): b*256 + i*16 + j

  float acc[16];
#pragma unroll
  for (int b = 0; b < 16; ++b) acc[b] = 0.f;

#pragma unroll
  for (int i = 0; i < 16; ++i) {
    float p[16];
#pragma unroll
    for (int j = 0; j < 16; ++j) p[j] = l[i] * r[j];
#pragma unroll
    for (int b = 0; b < 16; ++b) {
      const float* __restrict__ Wb = W + b * 256 + i * 16;  // block-uniform address
#pragma unroll
      for (int j = 0; j < 16; ++j) acc[b] += Wb[j] * p[j];
    }
  }

  float* op = out + ((long)site * nbOut + nOff + nloc) * 16;
#pragma unroll
  for (int c = 0; c < 4; ++c) {
    f4 v = {acc[4 * c + 0], acc[4 * c + 1], acc[4 * c + 2], acc[4 * c + 3]};
    *reinterpret_cast<f4*>(op + 4 * c) = v;
  }
}

// ---------------- Layer 11: in_dim=16, bond=1, writes d_out ----------------
__global__ __launch_bounds__(256) void ttn_l11(
    const float* __restrict__ in, float* __restrict__ out,
    const float* __restrict__ w)
{
  const int n = blockIdx.x * 256 + threadIdx.x;
  const float* lp = in + ((long)0 * NB + n) * 16;
  const float* rp = in + ((long)1 * NB + n) * 16;
  float l[16], r[16];
#pragma unroll
  for (int c = 0; c < 4; ++c) {
    f4 lv = *reinterpret_cast<const f4*>(lp + 4 * c);
    f4 rv = *reinterpret_cast<const f4*>(rp + 4 * c);
    l[4 * c + 0] = lv.x; l[4 * c + 1] = lv.y; l[4 * c + 2] = lv.z; l[4 * c + 3] = lv.w;
    r[4 * c + 0] = rv.x; r[4 * c + 1] = rv.y; r[4 * c + 2] = rv.z; r[4 * c + 3] = rv.w;
  }
  float acc = 0.f;
#pragma unroll
  for (int i = 0; i < 16; ++i) {
#pragma unroll
    for (int j = 0; j < 16; ++j) acc += w[i * 16 + j] * (l[i] * r[j]);
  }
  out[n] = acc;
}

extern "C" void kernel_launch(void* const* d_in, const int* in_sizes, int n_in,
                              void* d_out, int out_size, void* d_ws, size_t ws_size,
                              hipStream_t stream) {
  const float* x = (const float*)d_in[0];
  const float* w[12];
  for (int k = 0; k < 12; ++k) w[k] = (const float*)d_in[1 + k];

  // Workspace (floats): A: 2048*CHUNK*16 = 8.39M (33.5 MB)
  //                     B: 1024*CHUNK*16 = 4.19M (16.8 MB)
  //                     C: 128*NB*16     = 4.19M (16.8 MB)   total 67.1 MB
  float* A = (float*)d_ws;
  float* B = A + (size_t)2048 * CHUNK * 16;
  float* C = B + (size_t)1024 * CHUNK * 16;

  // ---- Phase 1: chunked L0..L4 ----
  for (int c = 0; c < NB / CHUNK; ++c) {
    const int n0 = c * CHUNK;
    ttn_l0<<<dim3(32, CHUNK / 4), 256, 0, stream>>>(x, A, w[0], n0);
    // L1: (32,64)->(32,32) pair W
    ttn_layer<<<dim3(1024, 1), 256, 0, stream>>>(A, B, w[1], 32, 64, 1, CHUNK, CHUNK, 0);
    // L2: (32,32)->(16,32) pair H
    ttn_layer<<<dim3(512, 1), 256, 0, stream>>>(B, A, w[2], 32, 32, 0, CHUNK, CHUNK, 0);
    // L3: (16,32)->(16,16) pair W
    ttn_layer<<<dim3(256, 1), 256, 0, stream>>>(A, B, w[3], 16, 32, 1, CHUNK, CHUNK, 0);
    // L4: (16,16)->(8,16) pair H -> full-batch buffer C at offset n0
    ttn_layer<<<dim3(128, 1), 256, 0, stream>>>(B, C, w[4], 16, 16, 0, CHUNK, NB, n0);
  }

  // ---- Phase 2: full-batch L5..L11 ----
  // L5: (8,16)->(8,8) pair W
  ttn_layer<<<dim3(64, NB / 256), 256, 0, stream>>>(C, A, w[5], 8, 16, 1, NB, NB, 0);
  // L6: (8,8)->(4,8) pair H
  ttn_layer<<<dim3(32, NB / 256), 256, 0, stream>>>(A, B, w[6], 8, 8, 0, NB, NB, 0);
  // L7: (4,8)->(4,4) pair W
  ttn_layer<<<dim3(16, NB / 256), 256, 0, stream>>>(B, A, w[7], 4, 8, 1, NB, NB, 0);
  // L8: (4,4)->(2,4) pair H
  ttn_layer<<<dim3(8, NB / 256), 256, 0, stream>>>(A, B, w[8], 4, 4, 0, NB, NB, 0);
  // L9: (2,4)->(2,2) pair W
  ttn_layer<<<dim3(4, NB / 256), 256, 0, stream>>>(B, A, w[9], 2, 4, 1, NB, NB, 0);
  // L10: (2,2)->(1,2) pair H
  ttn_layer<<<dim3(2, NB / 256), 256, 0, stream>>>(A, B, w[10], 2, 2, 0, NB, NB, 0);
  // L11: (1,2)->(1,1) pair W, bond=1 -> d_out
  ttn_l11<<<dim3(NB / 256), 256, 0, stream>>>(B, (float*)d_out, w[11]);
}

// Round 3
// 1058.119 us; speedup vs baseline: 2.6305x; 2.6305x over previous
//
#include <hip/hip_runtime.h>

// BinaryTTN on MI355X — round 3.
// R2 failure mode: block-uniform W -> scalar s_load streams, serialized lgkmcnt
// waits, VALUBusy <=30%, every layer dispatch ~150us. v2 kernel: W staged in LDS
// (wave-uniform broadcast ds_read_b128), 4n x 4b register tile per thread so each
// W read feeds 16 FMAs; all register arrays statically indexed under forced
// small unrolls (scratch-proof). Launch structure identical to passing R2.

#define NB 2048     // batch
#define CHUNK 256   // batch chunk for wide layers

typedef float f4 __attribute__((ext_vector_type(4)));

// ---------------- Layer 0: in_dim=2, pairs along H of the 64x64 grid ----------------
__global__ __launch_bounds__(256) void ttn_l0(
    const float* __restrict__ x, float* __restrict__ out,
    const float* __restrict__ w0, int n0)
{
  const int x0   = blockIdx.x;          // 0..31
  const int y    = threadIdx.x & 63;    // 0..63 (coalesced dim)
  const int nsub = threadIdx.x >> 6;    // 0..3
  const int nloc = blockIdx.y * 4 + nsub;   // 0..CHUNK-1
  const int n    = n0 + nloc;

  const float* xb = x + (long)n * 8192 + (2 * x0) * 64 + y;
  const float l0 = xb[0];
  const float l1 = xb[4096];
  const float r0 = xb[64];
  const float r1 = xb[4096 + 64];
  const float p00 = l0 * r0, p01 = l0 * r1, p10 = l1 * r0, p11 = l1 * r1;

  const float* wp = w0 + (long)(x0 * 64 + y) * 64;  // (b,i,j) = b*4 + i*2 + j
  float acc[16];
#pragma unroll
  for (int b = 0; b < 16; ++b) {
    acc[b] = wp[b * 4 + 0] * p00 + wp[b * 4 + 1] * p01 +
             wp[b * 4 + 2] * p10 + wp[b * 4 + 3] * p11;
  }

  float* op = out + ((long)(x0 * 64 + y) * CHUNK + nloc) * 16;
#pragma unroll
  for (int c = 0; c < 4; ++c) {
    f4 v = {acc[4 * c + 0], acc[4 * c + 1], acc[4 * c + 2], acc[4 * c + 3]};
    *reinterpret_cast<f4*>(op + 4 * c) = v;
  }
}

// ---------------- Generic layer v2: in_dim=16, bond=16 ----------------
// Block = 256 threads = 4 waves; one site x 256 n. Thread (nq, bh) computes
// 4 n (nq + 64k) x 4 b (bh*4+bb). W in LDS, read wave-uniform (broadcast).
__global__ __launch_bounds__(256) void ttn_layer2(
    const float* __restrict__ in, float* __restrict__ out,
    const float* __restrict__ w, int outW, int prevW, int pairW,
    int nbIn, int nbOut, int nOff)
{
  __shared__ float Wl[4096];  // 16 KB: (b,i,j) = b*256 + i*16 + j

  const int site = blockIdx.x;
  const int xs = site / outW;
  const int ys = site - xs * outW;
  int ls, rs;
  if (pairW) { ls = xs * prevW + 2 * ys; rs = ls + 1; }
  else       { ls = 2 * xs * prevW + ys; rs = ls + prevW; }

  const int tid = threadIdx.x;
  {
    const float* wsrc = w + (long)site * 4096;
#pragma unroll
    for (int kk = 0; kk < 4; ++kk) {
      const int fi = tid * 4 + kk * 1024;
      *reinterpret_cast<f4*>(&Wl[fi]) = *reinterpret_cast<const f4*>(wsrc + fi);
    }
  }
  __syncthreads();

  const int nq = tid & 63;   // lane within wave -> coalesced n
  const int bh = tid >> 6;   // wave id -> b-quarter (wave-uniform!)
  const int nbase = blockIdx.y * 256 + nq;

  const float* lp0 = in + ((long)ls * nbIn + nbase) * 16;
  const float* lp1 = lp0 + 64 * 16;
  const float* lp2 = lp0 + 128 * 16;
  const float* lp3 = lp0 + 192 * 16;
  const float* rp0 = in + ((long)rs * nbIn + nbase) * 16;

  // r fully register-resident: r[k][j]
  float r[4][16];
#pragma unroll
  for (int k = 0; k < 4; ++k) {
    const float* rp = rp0 + k * 64 * 16;
#pragma unroll
    for (int c = 0; c < 4; ++c) {
      f4 rv = *reinterpret_cast<const f4*>(rp + 4 * c);
      r[k][4 * c + 0] = rv.x; r[k][4 * c + 1] = rv.y;
      r[k][4 * c + 2] = rv.z; r[k][4 * c + 3] = rv.w;
    }
  }

  float acc[4][4];  // [k][bb]
#pragma unroll
  for (int k = 0; k < 4; ++k)
#pragma unroll
    for (int bb = 0; bb < 4; ++bb) acc[k][bb] = 0.f;

  for (int i = 0; i < 16; ++i) {
    // l re-loaded per i as scalars (L1 hits) -> no runtime-indexed array
    float lv0 = lp0[i], lv1 = lp1[i], lv2 = lp2[i], lv3 = lp3[i];
#pragma unroll
    for (int jc = 0; jc < 4; ++jc) {
      float t[4][4];
#pragma unroll
      for (int jj = 0; jj < 4; ++jj) {
        t[0][jj] = lv0 * r[0][jc * 4 + jj];
        t[1][jj] = lv1 * r[1][jc * 4 + jj];
        t[2][jj] = lv2 * r[2][jc * 4 + jj];
        t[3][jj] = lv3 * r[3][jc * 4 + jj];
      }
#pragma unroll
      for (int bb = 0; bb < 4; ++bb) {
        const int b = bh * 4 + bb;
        f4 W4 = *reinterpret_cast<const f4*>(&Wl[b * 256 + i * 16 + jc * 4]);
#pragma unroll
        for (int k = 0; k < 4; ++k) {
          acc[k][bb] += W4.x * t[k][0];
          acc[k][bb] += W4.y * t[k][1];
          acc[k][bb] += W4.z * t[k][2];
          acc[k][bb] += W4.w * t[k][3];
        }
      }
    }
  }

#pragma unroll
  for (int k = 0; k < 4; ++k) {
    const long nloc = nbase + 64 * k;
    f4 v = {acc[k][0], acc[k][1], acc[k][2], acc[k][3]};
    *reinterpret_cast<f4*>(out + ((long)site * nbOut + nOff + nloc) * 16 + bh * 4) = v;
  }
}

// ---------------- Layer 11: in_dim=16, bond=1, writes d_out ----------------
__global__ __launch_bounds__(256) void ttn_l11(
    const float* __restrict__ in, float* __restrict__ out,
    const float* __restrict__ w)
{
  const int n = blockIdx.x * 256 + threadIdx.x;
  const float* lp = in + ((long)0 * NB + n) * 16;
  const float* rp = in + ((long)1 * NB + n) * 16;
  float l[16], rr[16];
#pragma unroll
  for (int c = 0; c < 4; ++c) {
    f4 lv = *reinterpret_cast<const f4*>(lp + 4 * c);
    f4 rv = *reinterpret_cast<const f4*>(rp + 4 * c);
    l[4 * c + 0] = lv.x; l[4 * c + 1] = lv.y; l[4 * c + 2] = lv.z; l[4 * c + 3] = lv.w;
    rr[4 * c + 0] = rv.x; rr[4 * c + 1] = rv.y; rr[4 * c + 2] = rv.z; rr[4 * c + 3] = rv.w;
  }
  float acc = 0.f;
#pragma unroll
  for (int i = 0; i < 16; ++i) {
#pragma unroll
    for (int j = 0; j < 16; ++j) acc += w[i * 16 + j] * (l[i] * rr[j]);
  }
  out[n] = acc;
}

extern "C" void kernel_launch(void* const* d_in, const int* in_sizes, int n_in,
                              void* d_out, int out_size, void* d_ws, size_t ws_size,
                              hipStream_t stream) {
  const float* x = (const float*)d_in[0];
  const float* w[12];
  for (int k = 0; k < 12; ++k) w[k] = (const float*)d_in[1 + k];

  // Workspace (floats): A: 2048*CHUNK*16 = 8.39M (33.5 MB)
  //                     B: 1024*CHUNK*16 = 4.19M (16.8 MB)
  //                     C: 128*NB*16     = 4.19M (16.8 MB)   total 67.1 MB
  float* A = (float*)d_ws;
  float* B = A + (size_t)2048 * CHUNK * 16;
  float* C = B + (size_t)1024 * CHUNK * 16;

  // ---- Phase 1: chunked L0..L4 ----
  for (int c = 0; c < NB / CHUNK; ++c) {
    const int n0 = c * CHUNK;
    ttn_l0<<<dim3(32, CHUNK / 4), 256, 0, stream>>>(x, A, w[0], n0);
    ttn_layer2<<<dim3(1024, 1), 256, 0, stream>>>(A, B, w[1], 32, 64, 1, CHUNK, CHUNK, 0);
    ttn_layer2<<<dim3(512, 1), 256, 0, stream>>>(B, A, w[2], 32, 32, 0, CHUNK, CHUNK, 0);
    ttn_layer2<<<dim3(256, 1), 256, 0, stream>>>(A, B, w[3], 16, 32, 1, CHUNK, CHUNK, 0);
    ttn_layer2<<<dim3(128, 1), 256, 0, stream>>>(B, C, w[4], 16, 16, 0, CHUNK, NB, n0);
  }

  // ---- Phase 2: full-batch L5..L11 ----
  ttn_layer2<<<dim3(64, NB / 256), 256, 0, stream>>>(C, A, w[5], 8, 16, 1, NB, NB, 0);
  ttn_layer2<<<dim3(32, NB / 256), 256, 0, stream>>>(A, B, w[6], 8, 8, 0, NB, NB, 0);
  ttn_layer2<<<dim3(16, NB / 256), 256, 0, stream>>>(B, A, w[7], 4, 8, 1, NB, NB, 0);
  ttn_layer2<<<dim3(8, NB / 256), 256, 0, stream>>>(A, B, w[8], 4, 4, 0, NB, NB, 0);
  ttn_layer2<<<dim3(4, NB / 256), 256, 0, stream>>>(B, A, w[9], 2, 4, 1, NB, NB, 0);
  ttn_layer2<<<dim3(2, NB / 256), 256, 0, stream>>>(A, B, w[10], 2, 2, 0, NB, NB, 0);
  ttn_l11<<<dim3(NB / 256), 256, 0, stream>>>(B, (float*)d_out, w[11]);
}

// Round 4
// 698.258 us; speedup vs baseline: 3.9862x; 1.5154x over previous
//
#include <hip/hip_runtime.h>

// BinaryTTN on MI355X — round 4.
// R3: rolled i-loop w/ dependent per-i global loads -> VALUBusy 44%, 57us/dispatch.
// R4: (a) fuse L0 into L1 (x slice is 8 floats/n per block; W0 slices 128 floats in
// LDS) removing 536MB of A-buffer traffic; (b) 2n x 8b thread tile (half the l*r mul
// overhead); (c) i-loop fully unrolled, l/r register-resident, all indices static;
// (d) chunk size picked from ws_size (256 floor = 42MB, known-safe region).

#define NB 2048

typedef float f4 __attribute__((ext_vector_type(4)));

// ---------------- Fused L0+L1 ----------------
// Block = one L1 site (x1,y1) in 32x32 grid, 256 n. L0 sites (x1,2y1),(x1,2y1+1)
// computed in-register from x[n, c, 2x1..2x1+1, 2y1..2y1+1].
__global__ __launch_bounds__(256) void ttn_l0l1(
    const float* __restrict__ x, float* __restrict__ out,
    const float* __restrict__ w0, const float* __restrict__ w1,
    int nbOut, int n0)
{
  __shared__ float Wl[4096];   // W1[site]: (b,i,j) = b*256 + i*16 + j
  __shared__ float W0l[128];   // W0 for the two L0 sites (64 floats each)

  const int s1 = blockIdx.x;          // 0..1023
  const int x1 = s1 >> 5, y1 = s1 & 31;
  const int tid = threadIdx.x;
  {
    const float* wsrc = w1 + (long)s1 * 4096;
#pragma unroll
    for (int kk = 0; kk < 4; ++kk) {
      const int fi = tid * 4 + kk * 1024;
      *reinterpret_cast<f4*>(&Wl[fi]) = *reinterpret_cast<const f4*>(wsrc + fi);
    }
    if (tid < 32)
      *reinterpret_cast<f4*>(&W0l[tid * 4]) =
          *reinterpret_cast<const f4*>(w0 + ((long)(x1 * 64 + 2 * y1)) * 64 + tid * 4);
  }
  __syncthreads();

  const int lane = tid & 63;
  const int wv = tid >> 6;
  const int bh = (wv & 1) * 8;                          // b-offset (wave-uniform)
  const int nbL = blockIdx.y * 256 + (wv >> 1) * 128 + lane;  // chunk-local n (k=0)

  // ---- L0 in-register: produce l[k][16], r[k][16] ----
  float l[2][16], r[2][16];
#pragma unroll
  for (int k = 0; k < 2; ++k) {
    const float* xb = x + (long)(n0 + nbL + k * 64) * 8192 + (2 * x1) * 64 + 2 * y1;
    const float a00 = xb[0],    a01 = xb[1];      // c0, row 2x1,   cols 2y1,2y1+1
    const float a10 = xb[64],   a11 = xb[65];     // c0, row 2x1+1
    const float b00 = xb[4096], b01 = xb[4097];   // c1, row 2x1
    const float b10 = xb[4160], b11 = xb[4161];   // c1, row 2x1+1
    // site A (col 2y1): left=(a00,b00) right=(a10,b10); site B likewise col 2y1+1
    const float pA0 = a00 * a10, pA1 = a00 * b10, pA2 = b00 * a10, pA3 = b00 * b10;
    const float pB0 = a01 * a11, pB1 = a01 * b11, pB2 = b01 * a11, pB3 = b01 * b11;
#pragma unroll
    for (int b = 0; b < 16; ++b) {
      l[k][b] = W0l[b * 4 + 0] * pA0 + W0l[b * 4 + 1] * pA1 +
                W0l[b * 4 + 2] * pA2 + W0l[b * 4 + 3] * pA3;
      r[k][b] = W0l[64 + b * 4 + 0] * pB0 + W0l[64 + b * 4 + 1] * pB1 +
                W0l[64 + b * 4 + 2] * pB2 + W0l[64 + b * 4 + 3] * pB3;
    }
  }

  // ---- L1: 2n x 8b ----
  float acc[2][8];
#pragma unroll
  for (int k = 0; k < 2; ++k)
#pragma unroll
    for (int bb = 0; bb < 8; ++bb) acc[k][bb] = 0.f;

  const float* Wb = &Wl[bh * 256];
#pragma unroll
  for (int i = 0; i < 16; ++i) {
#pragma unroll
    for (int jc = 0; jc < 4; ++jc) {
      float p0[4], p1[4];
#pragma unroll
      for (int jj = 0; jj < 4; ++jj) {
        p0[jj] = l[0][i] * r[0][jc * 4 + jj];
        p1[jj] = l[1][i] * r[1][jc * 4 + jj];
      }
#pragma unroll
      for (int bb = 0; bb < 8; ++bb) {
        const f4 W4 = *reinterpret_cast<const f4*>(&Wb[bb * 256 + i * 16 + jc * 4]);
        acc[0][bb] += W4.x * p0[0]; acc[0][bb] += W4.y * p0[1];
        acc[0][bb] += W4.z * p0[2]; acc[0][bb] += W4.w * p0[3];
        acc[1][bb] += W4.x * p1[0]; acc[1][bb] += W4.y * p1[1];
        acc[1][bb] += W4.z * p1[2]; acc[1][bb] += W4.w * p1[3];
      }
    }
  }

#pragma unroll
  for (int k = 0; k < 2; ++k) {
    float* op = out + ((long)s1 * nbOut + nbL + k * 64) * 16 + bh;
    f4 v0 = {acc[k][0], acc[k][1], acc[k][2], acc[k][3]};
    f4 v1 = {acc[k][4], acc[k][5], acc[k][6], acc[k][7]};
    *reinterpret_cast<f4*>(op) = v0;
    *reinterpret_cast<f4*>(op + 4) = v1;
  }
}

// ---------------- Generic layer: in_dim=16, bond=16, 2n x 8b tile ----------------
__global__ __launch_bounds__(256) void ttn_layer3(
    const float* __restrict__ in, float* __restrict__ out,
    const float* __restrict__ w, int outW, int prevW, int pairW,
    int nbIn, int nbOut, int nOff)
{
  __shared__ float Wl[4096];

  const int site = blockIdx.x;
  const int xs = site / outW, ys = site - xs * outW;
  int ls, rs;
  if (pairW) { ls = xs * prevW + 2 * ys; rs = ls + 1; }
  else       { ls = 2 * xs * prevW + ys; rs = ls + prevW; }

  const int tid = threadIdx.x;
  {
    const float* wsrc = w + (long)site * 4096;
#pragma unroll
    for (int kk = 0; kk < 4; ++kk) {
      const int fi = tid * 4 + kk * 1024;
      *reinterpret_cast<f4*>(&Wl[fi]) = *reinterpret_cast<const f4*>(wsrc + fi);
    }
  }
  __syncthreads();

  const int lane = tid & 63;
  const int wv = tid >> 6;
  const int bh = (wv & 1) * 8;
  const int nbL = blockIdx.y * 256 + (wv >> 1) * 128 + lane;

  float l[2][16], r[2][16];
#pragma unroll
  for (int k = 0; k < 2; ++k) {
    const float* lp = in + ((long)ls * nbIn + nbL + k * 64) * 16;
    const float* rp = in + ((long)rs * nbIn + nbL + k * 64) * 16;
#pragma unroll
    for (int c = 0; c < 4; ++c) {
      f4 lv = *reinterpret_cast<const f4*>(lp + 4 * c);
      f4 rv = *reinterpret_cast<const f4*>(rp + 4 * c);
      l[k][4 * c + 0] = lv.x; l[k][4 * c + 1] = lv.y;
      l[k][4 * c + 2] = lv.z; l[k][4 * c + 3] = lv.w;
      r[k][4 * c + 0] = rv.x; r[k][4 * c + 1] = rv.y;
      r[k][4 * c + 2] = rv.z; r[k][4 * c + 3] = rv.w;
    }
  }

  float acc[2][8];
#pragma unroll
  for (int k = 0; k < 2; ++k)
#pragma unroll
    for (int bb = 0; bb < 8; ++bb) acc[k][bb] = 0.f;

  const float* Wb = &Wl[bh * 256];
#pragma unroll
  for (int i = 0; i < 16; ++i) {
#pragma unroll
    for (int jc = 0; jc < 4; ++jc) {
      float p0[4], p1[4];
#pragma unroll
      for (int jj = 0; jj < 4; ++jj) {
        p0[jj] = l[0][i] * r[0][jc * 4 + jj];
        p1[jj] = l[1][i] * r[1][jc * 4 + jj];
      }
#pragma unroll
      for (int bb = 0; bb < 8; ++bb) {
        const f4 W4 = *reinterpret_cast<const f4*>(&Wb[bb * 256 + i * 16 + jc * 4]);
        acc[0][bb] += W4.x * p0[0]; acc[0][bb] += W4.y * p0[1];
        acc[0][bb] += W4.z * p0[2]; acc[0][bb] += W4.w * p0[3];
        acc[1][bb] += W4.x * p1[0]; acc[1][bb] += W4.y * p1[1];
        acc[1][bb] += W4.z * p1[2]; acc[1][bb] += W4.w * p1[3];
      }
    }
  }

#pragma unroll
  for (int k = 0; k < 2; ++k) {
    float* op = out + ((long)site * nbOut + nOff + nbL + k * 64) * 16 + bh;
    f4 v0 = {acc[k][0], acc[k][1], acc[k][2], acc[k][3]};
    f4 v1 = {acc[k][4], acc[k][5], acc[k][6], acc[k][7]};
    *reinterpret_cast<f4*>(op) = v0;
    *reinterpret_cast<f4*>(op + 4) = v1;
  }
}

// ---------------- Layer 11: in_dim=16, bond=1, writes d_out ----------------
__global__ __launch_bounds__(256) void ttn_l11(
    const float* __restrict__ in, float* __restrict__ out,
    const float* __restrict__ w)
{
  const int n = blockIdx.x * 256 + threadIdx.x;
  const float* lp = in + ((long)0 * NB + n) * 16;
  const float* rp = in + ((long)1 * NB + n) * 16;
  float l[16], rr[16];
#pragma unroll
  for (int c = 0; c < 4; ++c) {
    f4 lv = *reinterpret_cast<const f4*>(lp + 4 * c);
    f4 rv = *reinterpret_cast<const f4*>(rp + 4 * c);
    l[4 * c + 0] = lv.x; l[4 * c + 1] = lv.y; l[4 * c + 2] = lv.z; l[4 * c + 3] = lv.w;
    rr[4 * c + 0] = rv.x; rr[4 * c + 1] = rv.y; rr[4 * c + 2] = rv.z; rr[4 * c + 3] = rv.w;
  }
  float acc = 0.f;
#pragma unroll
  for (int i = 0; i < 16; ++i) {
#pragma unroll
    for (int j = 0; j < 16; ++j) acc += w[i * 16 + j] * (l[i] * rr[j]);
  }
  out[n] = acc;
}

extern "C" void kernel_launch(void* const* d_in, const int* in_sizes, int n_in,
                              void* d_out, int out_size, void* d_ws, size_t ws_size,
                              hipStream_t stream) {
  const float* x = (const float*)d_in[0];
  const float* w[12];
  for (int k = 0; k < 12; ++k) w[k] = (const float*)d_in[1 + k];

  // Buffers (floats): B = 1024*C*16, D = 512*C*16, G = 128*2048*16 (4.19M).
  // ws bytes needed = (24576*C + 4194304) * 4. C=2048:218MB 1024:117 512:67 256:42.
  const size_t fl = ws_size / 4;
  int C = 256;
  if ((size_t)24576 * 2048 + 4194304 <= fl) C = 2048;
  else if ((size_t)24576 * 1024 + 4194304 <= fl) C = 1024;
  else if ((size_t)24576 * 512 + 4194304 <= fl) C = 512;

  float* B = (float*)d_ws;
  float* D = B + (size_t)1024 * C * 16;
  float* G = D + (size_t)512 * C * 16;
  const int nyc = C / 256;

  // ---- Phase 1: chunked fused L0L1 + L2..L4 ----
  for (int c = 0; c < NB / C; ++c) {
    const int n0 = c * C;
    ttn_l0l1<<<dim3(1024, nyc), 256, 0, stream>>>(x, B, w[0], w[1], C, n0);
    ttn_layer3<<<dim3(512, nyc), 256, 0, stream>>>(B, D, w[2], 32, 32, 0, C, C, 0);
    ttn_layer3<<<dim3(256, nyc), 256, 0, stream>>>(D, B, w[3], 16, 32, 1, C, C, 0);
    ttn_layer3<<<dim3(128, nyc), 256, 0, stream>>>(B, G, w[4], 16, 16, 0, C, NB, n0);
  }

  // ---- Phase 2: full batch ----
  ttn_layer3<<<dim3(64, NB / 256), 256, 0, stream>>>(G, B, w[5], 8, 16, 1, NB, NB, 0);
  ttn_layer3<<<dim3(32, NB / 256), 256, 0, stream>>>(B, D, w[6], 8, 8, 0, NB, NB, 0);
  ttn_layer3<<<dim3(16, NB / 256), 256, 0, stream>>>(D, B, w[7], 4, 8, 1, NB, NB, 0);
  ttn_layer3<<<dim3(8, NB / 256), 256, 0, stream>>>(B, D, w[8], 4, 4, 0, NB, NB, 0);
  ttn_layer3<<<dim3(4, NB / 256), 256, 0, stream>>>(D, B, w[9], 2, 4, 1, NB, NB, 0);
  ttn_layer3<<<dim3(2, NB / 256), 256, 0, stream>>>(B, D, w[10], 2, 2, 0, NB, NB, 0);
  ttn_l11<<<dim3(NB / 256), 256, 0, stream>>>(D, (float*)d_out, w[11]);
}

// Round 5
// 686.321 us; speedup vs baseline: 4.0555x; 1.0174x over previous
//
#include <hip/hip_runtime.h>

// BinaryTTN on MI355X — round 5.
// R4: fused l0l1 gathered x with lane=n (32KB stride) -> 330MB fetch, 420us.
// R5: (a) ttn_tx transposes x -> xT[site][n][8] (coalesced both sides; xT aliases
// the D buffer, ws stays 218MB = R4-proven); (b) l0l1 reads xT as 2 f4s;
// (c) generic layer: 2n x 16b/thread, i-loop ROLLED with l in LDS ([i][tid][k]
// float2) so no runtime-indexed register arrays; W broadcast ds_read_b128.

#define NB 2048

typedef float f4 __attribute__((ext_vector_type(4)));

// ---------------- Transpose: x (n,c,64,64) -> xT[site1][n][8] ----------------
// site1 = x1*32+y1; slots q = c*4 + r*2 + col, values x[n, c, 2x1+r, 2y1+col].
__global__ __launch_bounds__(256) void ttn_tx(
    const float* __restrict__ x, float* __restrict__ xT)
{
  const int x1 = blockIdx.x;            // 0..31
  const int y1 = threadIdx.x & 31;      // 0..31 (coalesced read dim)
  const int np = threadIdx.x >> 5;      // 0..7
  const int n  = blockIdx.y * 16 + np * 2;

  const float* xb = x + (long)n * 8192 + (2 * x1) * 64 + 2 * y1;
#pragma unroll
  for (int d = 0; d < 2; ++d) {
    const float* xd = xb + d * 8192;
    f4 q0 = {xd[0],    xd[1],    xd[64],   xd[65]};    // a00 a01 a10 a11
    f4 q1 = {xd[4096], xd[4097], xd[4160], xd[4161]};  // b00 b01 b10 b11
    float* op = xT + ((long)(x1 * 32 + y1) * NB + n + d) * 8;
    *reinterpret_cast<f4*>(op)     = q0;
    *reinterpret_cast<f4*>(op + 4) = q1;
  }
}

// ---------------- Fused L0+L1 (reads xT) ----------------
// Block = one L1 site x 512 n (4 waves x 128 n, 2 n per thread), 16 b per thread.
__global__ __launch_bounds__(256) void ttn_l0l1(
    const float* __restrict__ xT, float* __restrict__ out,
    const float* __restrict__ w0, const float* __restrict__ w1)
{
  __shared__ float Wl[4096];    // W1[site]: (b,i,j) = b*256 + i*16 + j
  __shared__ float W0l[128];    // W0 for the two L0 child sites
  __shared__ float Llds[8192];  // l[i][tid][k]

  const int s1 = blockIdx.x;
  const int x1 = s1 >> 5, y1 = s1 & 31;
  const int tid = threadIdx.x;
  {
    const float* wsrc = w1 + (long)s1 * 4096;
#pragma unroll
    for (int kk = 0; kk < 4; ++kk) {
      const int fi = tid * 4 + kk * 1024;
      *reinterpret_cast<f4*>(&Wl[fi]) = *reinterpret_cast<const f4*>(wsrc + fi);
    }
    if (tid < 32)
      *reinterpret_cast<f4*>(&W0l[tid * 4]) =
          *reinterpret_cast<const f4*>(w0 + ((long)(x1 * 64 + 2 * y1)) * 64 + tid * 4);
  }

  const int lane = tid & 63, wv = tid >> 6;
  const int nbL = blockIdx.y * 512 + wv * 128 + lane;

  float ltmp[2][16], r[2][16];
#pragma unroll
  for (int k = 0; k < 2; ++k) {
    const float* qp = xT + ((long)s1 * NB + nbL + 64 * k) * 8;
    f4 q0 = *reinterpret_cast<const f4*>(qp);
    f4 q1 = *reinterpret_cast<const f4*>(qp + 4);
    const float pA0 = q0.x * q0.z, pA1 = q0.x * q1.z,
                pA2 = q1.x * q0.z, pA3 = q1.x * q1.z;
    const float pB0 = q0.y * q0.w, pB1 = q0.y * q1.w,
                pB2 = q1.y * q0.w, pB3 = q1.y * q1.w;
    // needs W0l ready:
    if (k == 0) __syncthreads();  // covers Wl, W0l stage (before first use)
#pragma unroll
    for (int b = 0; b < 16; ++b) {
      ltmp[k][b] = W0l[b * 4 + 0] * pA0 + W0l[b * 4 + 1] * pA1 +
                   W0l[b * 4 + 2] * pA2 + W0l[b * 4 + 3] * pA3;
      r[k][b]    = W0l[64 + b * 4 + 0] * pB0 + W0l[64 + b * 4 + 1] * pB1 +
                   W0l[64 + b * 4 + 2] * pB2 + W0l[64 + b * 4 + 3] * pB3;
    }
  }
#pragma unroll
  for (int i = 0; i < 16; ++i)
    *reinterpret_cast<float2*>(&Llds[i * 512 + tid * 2]) =
        float2{ltmp[0][i], ltmp[1][i]};
  __syncthreads();

  float acc[2][16];
#pragma unroll
  for (int k = 0; k < 2; ++k)
#pragma unroll
    for (int bb = 0; bb < 16; ++bb) acc[k][bb] = 0.f;

  for (int i = 0; i < 16; ++i) {
    const float2 lv = *reinterpret_cast<const float2*>(&Llds[i * 512 + tid * 2]);
    const float* Wi = &Wl[i * 16];
#pragma unroll
    for (int jc = 0; jc < 4; ++jc) {
      float p0[4], p1[4];
#pragma unroll
      for (int jj = 0; jj < 4; ++jj) {
        p0[jj] = lv.x * r[0][jc * 4 + jj];
        p1[jj] = lv.y * r[1][jc * 4 + jj];
      }
#pragma unroll
      for (int bb = 0; bb < 16; ++bb) {
        const f4 W4 = *reinterpret_cast<const f4*>(&Wi[bb * 256 + jc * 4]);
        acc[0][bb] += W4.x * p0[0]; acc[0][bb] += W4.y * p0[1];
        acc[0][bb] += W4.z * p0[2]; acc[0][bb] += W4.w * p0[3];
        acc[1][bb] += W4.x * p1[0]; acc[1][bb] += W4.y * p1[1];
        acc[1][bb] += W4.z * p1[2]; acc[1][bb] += W4.w * p1[3];
      }
    }
  }

#pragma unroll
  for (int k = 0; k < 2; ++k) {
    float* op = out + ((long)s1 * NB + nbL + 64 * k) * 16;
#pragma unroll
    for (int c = 0; c < 4; ++c) {
      f4 v = {acc[k][c * 4 + 0], acc[k][c * 4 + 1],
              acc[k][c * 4 + 2], acc[k][c * 4 + 3]};
      *reinterpret_cast<f4*>(op + c * 4) = v;
    }
  }
}

// ---------------- Generic layer: in_dim=16, bond=16, 2n x 16b ----------------
__global__ __launch_bounds__(256) void ttn_layer4(
    const float* __restrict__ in, float* __restrict__ out,
    const float* __restrict__ w, int outW, int prevW, int pairW)
{
  __shared__ float Wl[4096];
  __shared__ float Llds[8192];

  const int site = blockIdx.x;
  const int xs = site / outW, ys = site - xs * outW;
  int ls, rs;
  if (pairW) { ls = xs * prevW + 2 * ys; rs = ls + 1; }
  else       { ls = 2 * xs * prevW + ys; rs = ls + prevW; }

  const int tid = threadIdx.x;
  {
    const float* wsrc = w + (long)site * 4096;
#pragma unroll
    for (int kk = 0; kk < 4; ++kk) {
      const int fi = tid * 4 + kk * 1024;
      *reinterpret_cast<f4*>(&Wl[fi]) = *reinterpret_cast<const f4*>(wsrc + fi);
    }
  }

  const int lane = tid & 63, wv = tid >> 6;
  const int nbL = blockIdx.y * 512 + wv * 128 + lane;

  float ltmp[2][16], r[2][16];
#pragma unroll
  for (int k = 0; k < 2; ++k) {
    const float* lp = in + ((long)ls * NB + nbL + 64 * k) * 16;
    const float* rp = in + ((long)rs * NB + nbL + 64 * k) * 16;
#pragma unroll
    for (int c = 0; c < 4; ++c) {
      f4 lv = *reinterpret_cast<const f4*>(lp + 4 * c);
      f4 rv = *reinterpret_cast<const f4*>(rp + 4 * c);
      ltmp[k][4 * c + 0] = lv.x; ltmp[k][4 * c + 1] = lv.y;
      ltmp[k][4 * c + 2] = lv.z; ltmp[k][4 * c + 3] = lv.w;
      r[k][4 * c + 0] = rv.x; r[k][4 * c + 1] = rv.y;
      r[k][4 * c + 2] = rv.z; r[k][4 * c + 3] = rv.w;
    }
  }
#pragma unroll
  for (int i = 0; i < 16; ++i)
    *reinterpret_cast<float2*>(&Llds[i * 512 + tid * 2]) =
        float2{ltmp[0][i], ltmp[1][i]};
  __syncthreads();

  float acc[2][16];
#pragma unroll
  for (int k = 0; k < 2; ++k)
#pragma unroll
    for (int bb = 0; bb < 16; ++bb) acc[k][bb] = 0.f;

  for (int i = 0; i < 16; ++i) {
    const float2 lv = *reinterpret_cast<const float2*>(&Llds[i * 512 + tid * 2]);
    const float* Wi = &Wl[i * 16];
#pragma unroll
    for (int jc = 0; jc < 4; ++jc) {
      float p0[4], p1[4];
#pragma unroll
      for (int jj = 0; jj < 4; ++jj) {
        p0[jj] = lv.x * r[0][jc * 4 + jj];
        p1[jj] = lv.y * r[1][jc * 4 + jj];
      }
#pragma unroll
      for (int bb = 0; bb < 16; ++bb) {
        const f4 W4 = *reinterpret_cast<const f4*>(&Wi[bb * 256 + jc * 4]);
        acc[0][bb] += W4.x * p0[0]; acc[0][bb] += W4.y * p0[1];
        acc[0][bb] += W4.z * p0[2]; acc[0][bb] += W4.w * p0[3];
        acc[1][bb] += W4.x * p1[0]; acc[1][bb] += W4.y * p1[1];
        acc[1][bb] += W4.z * p1[2]; acc[1][bb] += W4.w * p1[3];
      }
    }
  }

#pragma unroll
  for (int k = 0; k < 2; ++k) {
    float* op = out + ((long)site * NB + nbL + 64 * k) * 16;
#pragma unroll
    for (int c = 0; c < 4; ++c) {
      f4 v = {acc[k][c * 4 + 0], acc[k][c * 4 + 1],
              acc[k][c * 4 + 2], acc[k][c * 4 + 3]};
      *reinterpret_cast<f4*>(op + c * 4) = v;
    }
  }
}

// ---------------- Layer 11: in_dim=16, bond=1, writes d_out ----------------
__global__ __launch_bounds__(256) void ttn_l11(
    const float* __restrict__ in, float* __restrict__ out,
    const float* __restrict__ w)
{
  const int n = blockIdx.x * 256 + threadIdx.x;
  const float* lp = in + ((long)0 * NB + n) * 16;
  const float* rp = in + ((long)1 * NB + n) * 16;
  float l[16], rr[16];
#pragma unroll
  for (int c = 0; c < 4; ++c) {
    f4 lv = *reinterpret_cast<const f4*>(lp + 4 * c);
    f4 rv = *reinterpret_cast<const f4*>(rp + 4 * c);
    l[4 * c + 0] = lv.x; l[4 * c + 1] = lv.y; l[4 * c + 2] = lv.z; l[4 * c + 3] = lv.w;
    rr[4 * c + 0] = rv.x; rr[4 * c + 1] = rv.y; rr[4 * c + 2] = rv.z; rr[4 * c + 3] = rv.w;
  }
  float acc = 0.f;
#pragma unroll
  for (int i = 0; i < 16; ++i) {
#pragma unroll
    for (int j = 0; j < 16; ++j) acc += w[i * 16 + j] * (l[i] * rr[j]);
  }
  out[n] = acc;
}

extern "C" void kernel_launch(void* const* d_in, const int* in_sizes, int n_in,
                              void* d_out, int out_size, void* d_ws, size_t ws_size,
                              hipStream_t stream) {
  const float* x = (const float*)d_in[0];
  const float* w[12];
  for (int k = 0; k < 12; ++k) w[k] = (const float*)d_in[1 + k];

  // Buffers (floats). Total 218 MB — R4 ran with exactly this footprint (ws-proven).
  // xT (1024*2048*8) aliases D (512*2048*16): same size, xT dead before L2 writes D.
  float* B = (float*)d_ws;                       // 1024*2048*16 = 134.2 MB
  float* D = B + (size_t)1024 * NB * 16;         // 512*2048*16  =  67.1 MB (also xT)
  float* G = D + (size_t)512 * NB * 16;          // 128*2048*16  =  16.8 MB
  float* xT = D;

  ttn_tx<<<dim3(32, NB / 16), 256, 0, stream>>>(x, xT);
  ttn_l0l1<<<dim3(1024, NB / 512), 256, 0, stream>>>(xT, B, w[0], w[1]);

  const int ny = NB / 512;
  ttn_layer4<<<dim3(512, ny), 256, 0, stream>>>(B, D, w[2], 32, 32, 0);
  ttn_layer4<<<dim3(256, ny), 256, 0, stream>>>(D, B, w[3], 16, 32, 1);
  ttn_layer4<<<dim3(128, ny), 256, 0, stream>>>(B, G, w[4], 16, 16, 0);
  ttn_layer4<<<dim3(64,  ny), 256, 0, stream>>>(G, B, w[5], 8, 16, 1);
  ttn_layer4<<<dim3(32,  ny), 256, 0, stream>>>(B, D, w[6], 8, 8, 0);
  ttn_layer4<<<dim3(16,  ny), 256, 0, stream>>>(D, B, w[7], 4, 8, 1);
  ttn_layer4<<<dim3(8,   ny), 256, 0, stream>>>(B, D, w[8], 4, 4, 0);
  ttn_layer4<<<dim3(4,   ny), 256, 0, stream>>>(D, B, w[9], 2, 4, 1);
  ttn_layer4<<<dim3(2,   ny), 256, 0, stream>>>(B, D, w[10], 2, 2, 0);
  ttn_l11<<<dim3(NB / 256), 256, 0, stream>>>(D, (float*)d_out, w[11]);
}

// Round 6
// 646.959 us; speedup vs baseline: 4.3023x; 1.0608x over previous
//
#include <hip/hip_runtime.h>

// BinaryTTN on MI355X — round 6.
// R5: W-broadcast ds_read_b128 stream saturates the per-CU LDS pipe (LDS cyc
// model 336us ~= measured 310). LDS cost ∝ 1/nT. R6: nT=8 per thread, bT=8
// (2 waves/block), activations relaid as [site][d][n] so l/r stream as
// lane-coalesced dwords; jc-outer/i-rolled keeps registers static-indexed.
// Regions: R0 67MB + R1 134MB = 201MB < 218MB (R4-proven).

#define NB 2048

typedef float f4 __attribute__((ext_vector_type(4)));

// ---------------- Transpose: x (n,c,64,64) -> xT[site1][q][n] ----------------
// site1 = x1*32+y1 ; q = c*4 + r*2 + col ; value = x[n, c, 2x1+r, 2y1+col]
__global__ __launch_bounds__(256) void ttn_tx(
    const float* __restrict__ x, float* __restrict__ xT)
{
  __shared__ float S[4][32][65];  // 33.3 KB, padded (65) for bank-free column reads
  const int x1 = blockIdx.x;           // 0..31
  const int n0 = blockIdx.y * 32;      // n tile
  const int tid = threadIdx.x;
  const int lane = tid & 63;           // y (coalesced read dim)
  const int g = tid >> 6;              // 0..3 -> (c, r)
  const int c = g >> 1, rrow = g & 1;

  const float* xp = x + (long)n0 * 8192 + c * 4096 + (2 * x1 + rrow) * 64 + lane;
  for (int nn = 0; nn < 32; ++nn)
    S[g][nn][lane] = xp[(long)nn * 8192];
  __syncthreads();

  const int nl = tid & 31;             // n_loc (coalesced write dim)
  const int yg = tid >> 5;             // 0..7
  for (int yy = 0; yy < 4; ++yy) {
    const int y1 = yg * 4 + yy;
    float* op = xT + (long)(x1 * 32 + y1) * 8 * NB + n0 + nl;
#pragma unroll
    for (int q = 0; q < 8; ++q) {
      const int cc = q >> 2, rr2 = (q >> 1) & 1, col = q & 1;
      op[(long)q * NB] = S[cc * 2 + rr2][nl][2 * y1 + col];
    }
  }
}

// ---------------- Fused L0+L1 -> out[site1][b][n] ----------------
// Block 128 = 2 waves (b 0-7 / 8-15), 64 lanes x 8 n per thread.
__global__ __launch_bounds__(128) void ttn_l0l1(
    const float* __restrict__ xT, float* __restrict__ out,
    const float* __restrict__ w0, const float* __restrict__ w1)
{
  __shared__ float Wl[4096];   // W1[site]: (b,i,j) = b*256+i*16+j
  __shared__ float W0l[128];   // W0 child A (0..63) + child B (64..127)

  const int s1 = blockIdx.x;
  const int x1 = s1 >> 5, y1 = s1 & 31;
  const int tid = threadIdx.x;
  {
    const float* wsrc = w1 + (long)s1 * 4096;
#pragma unroll
    for (int kk = 0; kk < 8; ++kk) {
      const int fi = tid * 4 + kk * 512;
      *reinterpret_cast<f4*>(&Wl[fi]) = *reinterpret_cast<const f4*>(wsrc + fi);
    }
    if (tid < 32)
      *reinterpret_cast<f4*>(&W0l[tid * 4]) =
          *reinterpret_cast<const f4*>(w0 + (long)(x1 * 64 + 2 * y1) * 64 + tid * 4);
  }
  __syncthreads();

  const int lane = tid & 63;
  const int boff = (tid >> 6) * 8;
  const long n0 = (long)blockIdx.y * 512 + lane;
  const float* xb = xT + (long)s1 * 8 * NB + n0;

  // L0 products: pA (child A, col 2y1), pB (child B, col 2y1+1)
  float pA[8][4], pB[8][4];
#pragma unroll
  for (int k = 0; k < 8; ++k) {
    const float q0 = xb[0 * NB + 64 * k], q2 = xb[2 * NB + 64 * k],
                q4 = xb[4 * NB + 64 * k], q6 = xb[6 * NB + 64 * k];
    const float q1 = xb[1 * NB + 64 * k], q3 = xb[3 * NB + 64 * k],
                q5 = xb[5 * NB + 64 * k], q7 = xb[7 * NB + 64 * k];
    pA[k][0] = q0 * q2; pA[k][1] = q0 * q6; pA[k][2] = q4 * q2; pA[k][3] = q4 * q6;
    pB[k][0] = q1 * q3; pB[k][1] = q1 * q7; pB[k][2] = q5 * q3; pB[k][3] = q5 * q7;
  }

  float acc[8][8];
#pragma unroll
  for (int k = 0; k < 8; ++k)
#pragma unroll
    for (int bb = 0; bb < 8; ++bb) acc[k][bb] = 0.f;

  for (int jc = 0; jc < 4; ++jc) {
    float rr[8][4];
#pragma unroll
    for (int jj = 0; jj < 4; ++jj) {
      const int j = jc * 4 + jj;
      const float wa = W0l[64 + j * 4 + 0], wb = W0l[64 + j * 4 + 1],
                  wc = W0l[64 + j * 4 + 2], wd = W0l[64 + j * 4 + 3];
#pragma unroll
      for (int k = 0; k < 8; ++k)
        rr[k][jj] = wa * pB[k][0] + wb * pB[k][1] + wc * pB[k][2] + wd * pB[k][3];
    }
    for (int i = 0; i < 16; ++i) {
      const float u0 = W0l[i * 4 + 0], u1 = W0l[i * 4 + 1],
                  u2 = W0l[i * 4 + 2], u3 = W0l[i * 4 + 3];
      float lk[8];
#pragma unroll
      for (int k = 0; k < 8; ++k)
        lk[k] = u0 * pA[k][0] + u1 * pA[k][1] + u2 * pA[k][2] + u3 * pA[k][3];
      f4 Wreg[8];
#pragma unroll
      for (int bb = 0; bb < 8; ++bb)
        Wreg[bb] = *reinterpret_cast<const f4*>(&Wl[(boff + bb) * 256 + i * 16 + jc * 4]);
#pragma unroll
      for (int k = 0; k < 8; ++k) {
        const float p0 = lk[k] * rr[k][0], p1 = lk[k] * rr[k][1],
                    p2 = lk[k] * rr[k][2], p3 = lk[k] * rr[k][3];
#pragma unroll
        for (int bb = 0; bb < 8; ++bb) {
          acc[k][bb] += Wreg[bb].x * p0; acc[k][bb] += Wreg[bb].y * p1;
          acc[k][bb] += Wreg[bb].z * p2; acc[k][bb] += Wreg[bb].w * p3;
        }
      }
    }
  }

  float* obase = out + ((long)s1 * 16 + boff) * NB + n0;
#pragma unroll
  for (int bb = 0; bb < 8; ++bb)
#pragma unroll
    for (int k = 0; k < 8; ++k)
      obase[(long)bb * NB + 64 * k] = acc[k][bb];
}

// ---------------- Generic layer: [site][d][n] layout, NT n per thread ----------------
template <int NT>
__global__ __launch_bounds__(128) void ttn_layer(
    const float* __restrict__ in, float* __restrict__ out,
    const float* __restrict__ w, int outW, int prevW, int pairW)
{
  __shared__ float Wl[4096];

  const int site = blockIdx.x;
  const int xs = site / outW, ys = site - xs * outW;
  int ls, rs;
  if (pairW) { ls = xs * prevW + 2 * ys; rs = ls + 1; }
  else       { ls = 2 * xs * prevW + ys; rs = ls + prevW; }

  const int tid = threadIdx.x;
  {
    const float* wsrc = w + (long)site * 4096;
#pragma unroll
    for (int kk = 0; kk < 8; ++kk) {
      const int fi = tid * 4 + kk * 512;
      *reinterpret_cast<f4*>(&Wl[fi]) = *reinterpret_cast<const f4*>(wsrc + fi);
    }
  }
  __syncthreads();

  const int lane = tid & 63;
  const int boff = (tid >> 6) * 8;
  const long n0 = (long)blockIdx.y * (64 * NT) + lane;
  const float* lbase = in + (long)ls * 16 * NB + n0;
  const float* rbase = in + (long)rs * 16 * NB + n0;

  float acc[NT][8];
#pragma unroll
  for (int k = 0; k < NT; ++k)
#pragma unroll
    for (int bb = 0; bb < 8; ++bb) acc[k][bb] = 0.f;

  for (int jc = 0; jc < 4; ++jc) {
    float rr[NT][4];
#pragma unroll
    for (int jj = 0; jj < 4; ++jj) {
      const float* rp = rbase + (long)(jc * 4 + jj) * NB;
#pragma unroll
      for (int k = 0; k < NT; ++k) rr[k][jj] = rp[64 * k];
    }
    for (int i = 0; i < 16; ++i) {
      const float* lp = lbase + (long)i * NB;
      float lk[NT];
#pragma unroll
      for (int k = 0; k < NT; ++k) lk[k] = lp[64 * k];
      f4 Wreg[8];
#pragma unroll
      for (int bb = 0; bb < 8; ++bb)
        Wreg[bb] = *reinterpret_cast<const f4*>(&Wl[(boff + bb) * 256 + i * 16 + jc * 4]);
#pragma unroll
      for (int k = 0; k < NT; ++k) {
        const float p0 = lk[k] * rr[k][0], p1 = lk[k] * rr[k][1],
                    p2 = lk[k] * rr[k][2], p3 = lk[k] * rr[k][3];
#pragma unroll
        for (int bb = 0; bb < 8; ++bb) {
          acc[k][bb] += Wreg[bb].x * p0; acc[k][bb] += Wreg[bb].y * p1;
          acc[k][bb] += Wreg[bb].z * p2; acc[k][bb] += Wreg[bb].w * p3;
        }
      }
    }
  }

  float* obase = out + ((long)site * 16 + boff) * NB + n0;
#pragma unroll
  for (int bb = 0; bb < 8; ++bb)
#pragma unroll
    for (int k = 0; k < NT; ++k)
      obase[(long)bb * NB + 64 * k] = acc[k][bb];
}

// ---------------- Layer 11: bond=1 -> d_out ----------------
__global__ __launch_bounds__(256) void ttn_l11(
    const float* __restrict__ in, float* __restrict__ out,
    const float* __restrict__ w)
{
  __shared__ float Wl[256];
  const int tid = threadIdx.x;
  if (tid < 64)
    *reinterpret_cast<f4*>(&Wl[tid * 4]) = *reinterpret_cast<const f4*>(w + tid * 4);
  __syncthreads();

  const long n = (long)blockIdx.x * 256 + tid;
  float l[16], r[16];
#pragma unroll
  for (int i = 0; i < 16; ++i) l[i] = in[(long)i * NB + n];
#pragma unroll
  for (int j = 0; j < 16; ++j) r[j] = in[(long)(16 + j) * NB + n];
  float acc = 0.f;
#pragma unroll
  for (int i = 0; i < 16; ++i)
#pragma unroll
    for (int j = 0; j < 16; ++j) acc += Wl[i * 16 + j] * (l[i] * r[j]);
  out[n] = acc;
}

extern "C" void kernel_launch(void* const* d_in, const int* in_sizes, int n_in,
                              void* d_out, int out_size, void* d_ws, size_t ws_size,
                              hipStream_t stream) {
  const float* x = (const float*)d_in[0];
  const float* w[12];
  for (int k = 0; k < 12; ++k) w[k] = (const float*)d_in[1 + k];

  // R0: 16.78M floats (67.1 MB)  — xT, then L2/L4/... outputs
  // R1: 33.55M floats (134.2 MB) — L1/L3/... outputs.  Total 201 MB (<218 proven).
  float* R0 = (float*)d_ws;
  float* R1 = R0 + (size_t)1024 * 8 * NB;

  ttn_tx<<<dim3(32, NB / 32), 256, 0, stream>>>(x, R0);
  ttn_l0l1<<<dim3(1024, 4), 128, 0, stream>>>(R0, R1, w[0], w[1]);

  ttn_layer<8><<<dim3(512, 4), 128, 0, stream>>>(R1, R0, w[2], 32, 32, 0);   // L2
  ttn_layer<8><<<dim3(256, 4), 128, 0, stream>>>(R0, R1, w[3], 16, 32, 1);   // L3
  ttn_layer<8><<<dim3(128, 4), 128, 0, stream>>>(R1, R0, w[4], 16, 16, 0);   // L4
  ttn_layer<8><<<dim3(64, 4), 128, 0, stream>>>(R0, R1, w[5], 8, 16, 1);     // L5
  ttn_layer<4><<<dim3(32, 8), 128, 0, stream>>>(R1, R0, w[6], 8, 8, 0);      // L6
  ttn_layer<2><<<dim3(16, 16), 128, 0, stream>>>(R0, R1, w[7], 4, 8, 1);     // L7
  ttn_layer<2><<<dim3(8, 16), 128, 0, stream>>>(R1, R0, w[8], 4, 4, 0);      // L8
  ttn_layer<1><<<dim3(4, 32), 128, 0, stream>>>(R0, R1, w[9], 2, 4, 1);      // L9
  ttn_layer<1><<<dim3(2, 32), 128, 0, stream>>>(R1, R0, w[10], 2, 2, 0);     // L10
  ttn_l11<<<dim3(NB / 256), 256, 0, stream>>>(R0, (float*)d_out, w[11]);
}